// Round 7
// baseline (314.245 us; speedup 1.0000x reference)
//
#include <hip/hip_runtime.h>
#include <stdint.h>

#define B_    8
#define N_    512
#define DIN   1024
#define DOUT  1024
#define L_    16
#define T_    4096

#define WMR 64                   /* wave tile: 64 rows x 64 cols */
#define MT_PAD 544               /* max 64-row m-tiles, multiple of 32 */
#define MB_PER_NT (MT_PAD / 4)   /* 136 blocks per n-tile column */
#define ZROW ((long)B_ * N_)     /* zero-row index in pooled_bf16 */

typedef __attribute__((ext_vector_type(8))) short short8;
typedef __attribute__((ext_vector_type(4))) float f32x4;

#define POOLED_ELEMS ((long)B_ * N_ * DIN + DIN)
#define WS_W_OFF     ((size_t)POOLED_ELEMS * 2)
#define WS_META_OFF  (WS_W_OFF + (size_t)L_ * DOUT * DIN * 2)

__device__ __forceinline__ unsigned short f2bf(float f) {
  unsigned u = __float_as_uint(f);
  u += 0x7FFFu + ((u >> 16) & 1u);   /* RNE */
  return (unsigned short)(u >> 16);
}

/* ---------------- kernel 1: fp32 -> bf16 conversion ---------------- */
__global__ void k_convert(const float* __restrict__ pooled,
                          const float* __restrict__ W,
                          unsigned short* __restrict__ wsP,
                          unsigned short* __restrict__ wsW) {
  const long np4 = (long)B_ * N_ * DIN / 4;
  const long nw4 = (long)L_ * DOUT * DIN / 4;
  const long nz4 = DIN / 4;
  long i = (long)blockIdx.x * blockDim.x + threadIdx.x;
  const long stride = (long)gridDim.x * blockDim.x;
  for (; i < np4 + nw4 + nz4; i += stride) {
    if (i < np4) {
      float4 v = ((const float4*)pooled)[i];
      ushort4 o = { f2bf(v.x), f2bf(v.y), f2bf(v.z), f2bf(v.w) };
      ((ushort4*)wsP)[i] = o;
    } else if (i < np4 + nw4) {
      float4 v = ((const float4*)W)[i - np4];
      ushort4 o = { f2bf(v.x), f2bf(v.y), f2bf(v.z), f2bf(v.w) };
      ((ushort4*)wsW)[i - np4] = o;
    } else {
      ushort4 z = {0, 0, 0, 0};
      ((ushort4*)wsP)[i - nw4] = z;
    }
  }
}

/* ---------------- kernel 2: dedup prep (64-row tile granularity) ------------
   Entry = t(12) | n(10) | rep(8).  Per segment n: positions 0..14 unique
   (rep=1, group l=pos); positions >=15 share one output row -> group 15
   entries with rep (split at 255). Invalid t's -> zero-row (n=1023).        */
__global__ void k_prep(const int* __restrict__ pidx,
                       unsigned* __restrict__ tlist,
                       int* __restrict__ goff, int* __restrict__ grows,
                       unsigned* __restrict__ table, int* __restrict__ ntiles) {
  __shared__ int sp[N_];
  __shared__ int cnt[L_], pos[L_];
  const int tid = threadIdx.x;          /* 512 threads, one per segment */
  if (tid < N_) sp[tid] = pidx[tid];
  if (tid < L_) cnt[tid] = 0;
  __syncthreads();

  int start = tid ? sp[tid - 1] + 1 : 0;
  int len = sp[tid] - start + 1;
  if (len < 0) len = 0;
  const int nfull = len < 15 ? len : 15;

  for (int l2 = 0; l2 < nfull; ++l2) atomicAdd(&cnt[l2], 1);
  if (len > 15) atomicAdd(&cnt[15], (len - 15 + 254) / 255);
  if (tid == N_ - 1) {
    int invlen = T_ - 1 - sp[N_ - 1];
    if (invlen > 0) atomicAdd(&cnt[15], (invlen + 254) / 255);
  }
  __syncthreads();
  if (tid == 0) {
    int off = 0;
    for (int l2 = 0; l2 < L_; ++l2) {
      pos[l2] = off; goff[l2] = off; grows[l2] = cnt[l2] * B_;
      off += cnt[l2];
    }
  }
  __syncthreads();

  for (int l2 = 0; l2 < nfull; ++l2) {
    int p = atomicAdd(&pos[l2], 1);
    tlist[p] = (unsigned)(start + l2) | ((unsigned)tid << 12) | (1u << 22);
  }
  if (len > 15) {
    int rem = len - 15, tt2 = start + 15;
    while (rem > 0) {
      int rr = rem > 255 ? 255 : rem;
      int p = atomicAdd(&pos[15], 1);
      tlist[p] = (unsigned)tt2 | ((unsigned)tid << 12) | ((unsigned)rr << 22);
      tt2 += rr; rem -= rr;
    }
  }
  if (tid == N_ - 1) {
    int tt2 = sp[N_ - 1] + 1;
    int rem = T_ - tt2;
    while (rem > 0) {
      int rr = rem > 255 ? 255 : rem;
      int p = atomicAdd(&pos[15], 1);
      tlist[p] = (unsigned)tt2 | (1023u << 12) | ((unsigned)rr << 22);
      tt2 += rr; rem -= rr;
    }
  }
  __syncthreads();
  if (tid == 0) {
    int tt = 0;
    for (int l2 = 0; l2 < L_; ++l2) {
      int rows = cnt[l2] * B_;
      for (int r0 = 0; r0 < rows; r0 += WMR) table[tt++] = (unsigned)l2 | ((unsigned)r0 << 4);
    }
    *ntiles = tt;
  }
}

/* ---------------- kernel 3: barrier-free LDS-free gather-GEMM ----------
   One WAVE = one 64x64 output tile; 4 independent waves per block (no
   __syncthreads anywhere). MFMA operands load straight from L2 via
   global_load_dwordx4 (fragment = 16B contiguous per lane for both A and
   B in the verified 16x16x32 layout). K fully unrolled, 32 steps, double-
   buffered frag sets, compiler-scheduled vmcnt. Dedup rep-write epilogue. */
__global__ __launch_bounds__(256, 2)
void k_gemm(const unsigned short* __restrict__ wsP,
            const unsigned short* __restrict__ wsW,
            const unsigned* __restrict__ tlist,
            const int* __restrict__ goff,
            const int* __restrict__ grows,
            const unsigned* __restrict__ table,
            const int* __restrict__ ntiles,
            float* __restrict__ out) {
  const int w     = threadIdx.x >> 6;
  const int lane  = threadIdx.x & 63;
  const int ntile = blockIdx.x / MB_PER_NT;              /* 0..15 */
  const int mtile = (blockIdx.x % MB_PER_NT) * 4 + w;    /* mtile-major mod 8 -> XCD */
  if (mtile >= *ntiles) return;      /* per-wave exit; no barriers -> safe */

  const unsigned te = table[mtile];
  const int l    = te & 15;
  const int row0 = (int)(te >> 4);
  const int toff = goff[l];
  const int rows = grows[l];

  const int lr = lane & 15;          /* row/col within 16-frag */
  const int kh = lane >> 4;          /* k-half: k-offset kh*8 elems */

  /* A fragment base pointers: 4 gathered rows per lane */
  const unsigned short* pa[4];
#pragma unroll
  for (int m = 0; m < 4; ++m) {
    int rg = row0 + m * 16 + lr;
    long rowElem;
    if (rg < rows) {
      unsigned e = tlist[toff + (rg >> 3)];
      unsigned n = (e >> 12) & 0x3FF;
      int b = rg & 7;
      rowElem = (n >= N_) ? ZROW * (long)DIN
                          : ((long)(b * N_ + (int)n)) * DIN;
    } else rowElem = ZROW * (long)DIN;
    pa[m] = wsP + rowElem + kh * 8;
  }
  /* B fragment base pointers: W rows (output channels), k contiguous */
  const unsigned short* pb[4];
#pragma unroll
  for (int n = 0; n < 4; ++n)
    pb[n] = wsW + ((long)l * DOUT + ntile * 64 + n * 16 + lr) * DIN + kh * 8;

  f32x4 acc[4][4];
#pragma unroll
  for (int m = 0; m < 4; ++m)
#pragma unroll
    for (int n = 0; n < 4; ++n)
      acc[m][n] = (f32x4){0.f, 0.f, 0.f, 0.f};

  short8 a0[4], b0[4], a1[4], b1[4];
#pragma unroll
  for (int m = 0; m < 4; ++m) {
    a0[m] = *(const short8*)(pa[m]);
    a1[m] = *(const short8*)(pa[m] + 32);
  }
#pragma unroll
  for (int n = 0; n < 4; ++n) {
    b0[n] = *(const short8*)(pb[n]);
    b1[n] = *(const short8*)(pb[n] + 32);
  }

#pragma unroll
  for (int s = 0; s < 32; s += 2) {
    /* consume set0 (K-step s), prefetch set0 <- step s+2 */
#pragma unroll
    for (int n = 0; n < 4; ++n)
#pragma unroll
      for (int m = 0; m < 4; ++m)
        acc[m][n] = __builtin_amdgcn_mfma_f32_16x16x32_bf16(a0[m], b0[n], acc[m][n], 0, 0, 0);
    if (s + 2 < 32) {
#pragma unroll
      for (int m = 0; m < 4; ++m) a0[m] = *(const short8*)(pa[m] + (s + 2) * 32);
#pragma unroll
      for (int n = 0; n < 4; ++n) b0[n] = *(const short8*)(pb[n] + (s + 2) * 32);
    }
    /* consume set1 (K-step s+1), prefetch set1 <- step s+3 */
#pragma unroll
    for (int n = 0; n < 4; ++n)
#pragma unroll
      for (int m = 0; m < 4; ++m)
        acc[m][n] = __builtin_amdgcn_mfma_f32_16x16x32_bf16(a1[m], b1[n], acc[m][n], 0, 0, 0);
    if (s + 3 < 32) {
#pragma unroll
      for (int m = 0; m < 4; ++m) a1[m] = *(const short8*)(pa[m] + (s + 3) * 32);
#pragma unroll
      for (int n = 0; n < 4; ++n) b1[n] = *(const short8*)(pb[n] + (s + 3) * 32);
    }
  }

  /* ---- epilogue: C/D layout col=lane&15, row=(lane>>4)*4+j; rep-write ---- */
#pragma unroll
  for (int m = 0; m < 4; ++m) {
#pragma unroll
    for (int jj = 0; jj < 4; ++jj) {
      int rg = row0 + m * 16 + (lane >> 4) * 4 + jj;
      if (rg >= rows) continue;
      unsigned e = tlist[toff + (rg >> 3)];
      int b = rg & 7;
      int t0 = (int)(e & 0xFFFu);
      int rep = (int)(e >> 22);
      float* orow = out + ((long)b * T_ + t0) * DOUT + ntile * 64 + lr;
      for (int r = 0; r < rep; ++r) {
#pragma unroll
        for (int n = 0; n < 4; ++n)
          orow[n * 16] = acc[m][n][jj];
        orow += DOUT;
      }
    }
  }
}

/* ---------------- launch ---------------- */
extern "C" void kernel_launch(void* const* d_in, const int* in_sizes, int n_in,
                              void* d_out, int out_size, void* d_ws, size_t ws_size,
                              hipStream_t stream) {
  const float* pooled = (const float*)d_in[0];
  const float* W      = (const float*)d_in[1];
  const int*   pidx   = (const int*)d_in[2];
  float* out = (float*)d_out;

  char* ws = (char*)d_ws;
  unsigned short* wsP = (unsigned short*)(ws);
  unsigned short* wsW = (unsigned short*)(ws + WS_W_OFF);
  int* meta  = (int*)(ws + WS_META_OFF);
  unsigned* tlist = (unsigned*)meta;
  int* goff  = meta + 8 * T_;
  int* grows = meta + 8 * T_ + 16;
  unsigned* table = (unsigned*)(meta + 8 * T_ + 32);
  int* ntiles = meta + 8 * T_ + 32 + MT_PAD;

  k_prep<<<1, 512, 0, stream>>>(pidx, tlist, goff, grows, table, ntiles);
  k_convert<<<2048, 256, 0, stream>>>(pooled, W, wsP, wsW);
  k_gemm<<<16 * MB_PER_NT, 256, 0, stream>>>(wsP, wsW, tlist, goff, grows,
                                             table, ntiles, out);
}

// Round 8
// 134.626 us; speedup vs baseline: 2.3342x; 2.3342x over previous
//
#include <hip/hip_runtime.h>
#include <stdint.h>

#define B_    8
#define N_    512
#define DIN   1024
#define DOUT  1024
#define L_    16
#define T_    4096

#define BM 128
#define BN 128
#define BK 32
#define NB (DOUT / BN)          /* 8 */
#define NKT (DIN / BK)          /* 32 K-tiles */
#define MT_MAX 288              /* sum ceil(rows_l/128) <= 256+16 partials */
#define ZROW ((long)B_ * N_)    /* zero-row index in pooled_bf16 */

typedef __attribute__((ext_vector_type(8))) short short8;
typedef __attribute__((ext_vector_type(4))) float f32x4;

#define POOLED_ELEMS ((long)B_ * N_ * DIN + DIN)
#define WS_W_OFF     ((size_t)POOLED_ELEMS * 2)
#define WS_META_OFF  (WS_W_OFF + (size_t)L_ * DOUT * DIN * 2)

__device__ __forceinline__ unsigned short f2bf(float f) {
  unsigned u = __float_as_uint(f);
  u += 0x7FFFu + ((u >> 16) & 1u);   /* RNE */
  return (unsigned short)(u >> 16);
}

__device__ __forceinline__ void gload_lds16(const void* g, void* l) {
  __builtin_amdgcn_global_load_lds(
      (const __attribute__((address_space(1))) void*)g,
      (__attribute__((address_space(3))) void*)l, 16, 0, 0);
}

__device__ __forceinline__ void bar() {
  asm volatile("" ::: "memory");
  __builtin_amdgcn_s_barrier();
  asm volatile("" ::: "memory");
}

/* ---------------- kernel 1: fp32 -> bf16 conversion ---------------- */
__global__ void k_convert(const float* __restrict__ pooled,
                          const float* __restrict__ W,
                          unsigned short* __restrict__ wsP,
                          unsigned short* __restrict__ wsW) {
  const long np4 = (long)B_ * N_ * DIN / 4;
  const long nw4 = (long)L_ * DOUT * DIN / 4;
  const long nz4 = DIN / 4;
  long i = (long)blockIdx.x * blockDim.x + threadIdx.x;
  const long stride = (long)gridDim.x * blockDim.x;
  for (; i < np4 + nw4 + nz4; i += stride) {
    if (i < np4) {
      float4 v = ((const float4*)pooled)[i];
      ushort4 o = { f2bf(v.x), f2bf(v.y), f2bf(v.z), f2bf(v.w) };
      ((ushort4*)wsP)[i] = o;
    } else if (i < np4 + nw4) {
      float4 v = ((const float4*)W)[i - np4];
      ushort4 o = { f2bf(v.x), f2bf(v.y), f2bf(v.z), f2bf(v.w) };
      ((ushort4*)wsW)[i - np4] = o;
    } else {
      ushort4 z = {0, 0, 0, 0};
      ((ushort4*)wsP)[i - nw4] = z;
    }
  }
}

/* ---------------- kernel 2: dedup prep (128-row tile granularity) ----------
   Entry = t(12) | n(10) | rep(8). Positions 0..14 of a segment are unique
   rows (rep=1, group l=pos); positions >=15 share one output row -> group 15
   entries with rep (split at 255). Invalid t's -> zero-row (n=1023).        */
__global__ void k_prep(const int* __restrict__ pidx,
                       unsigned* __restrict__ tlist,
                       int* __restrict__ goff, int* __restrict__ grows,
                       unsigned* __restrict__ table, int* __restrict__ ntiles) {
  __shared__ int sp[N_];
  __shared__ int cnt[L_], pos[L_];
  const int tid = threadIdx.x;          /* 512 threads, one per segment */
  if (tid < N_) sp[tid] = pidx[tid];
  if (tid < L_) cnt[tid] = 0;
  __syncthreads();

  int start = tid ? sp[tid - 1] + 1 : 0;
  int len = sp[tid] - start + 1;
  if (len < 0) len = 0;
  const int nfull = len < 15 ? len : 15;

  for (int l2 = 0; l2 < nfull; ++l2) atomicAdd(&cnt[l2], 1);
  if (len > 15) atomicAdd(&cnt[15], (len - 15 + 254) / 255);
  if (tid == N_ - 1) {
    int invlen = T_ - 1 - sp[N_ - 1];
    if (invlen > 0) atomicAdd(&cnt[15], (invlen + 254) / 255);
  }
  __syncthreads();
  if (tid == 0) {
    int off = 0;
    for (int l2 = 0; l2 < L_; ++l2) {
      pos[l2] = off; goff[l2] = off; grows[l2] = cnt[l2] * B_;
      off += cnt[l2];
    }
  }
  __syncthreads();

  for (int l2 = 0; l2 < nfull; ++l2) {
    int p = atomicAdd(&pos[l2], 1);
    tlist[p] = (unsigned)(start + l2) | ((unsigned)tid << 12) | (1u << 22);
  }
  if (len > 15) {
    int rem = len - 15, tt2 = start + 15;
    while (rem > 0) {
      int rr = rem > 255 ? 255 : rem;
      int p = atomicAdd(&pos[15], 1);
      tlist[p] = (unsigned)tt2 | ((unsigned)tid << 12) | ((unsigned)rr << 22);
      tt2 += rr; rem -= rr;
    }
  }
  if (tid == N_ - 1) {
    int tt2 = sp[N_ - 1] + 1;
    int rem = T_ - tt2;
    while (rem > 0) {
      int rr = rem > 255 ? 255 : rem;
      int p = atomicAdd(&pos[15], 1);
      tlist[p] = (unsigned)tt2 | (1023u << 12) | ((unsigned)rr << 22);
      tt2 += rr; rem -= rr;
    }
  }
  __syncthreads();
  if (tid == 0) {
    int tt = 0;
    for (int l2 = 0; l2 < L_; ++l2) {
      int rows = cnt[l2] * B_;
      for (int r0 = 0; r0 < rows; r0 += BM) table[tt++] = (unsigned)l2 | ((unsigned)r0 << 4);
    }
    *ntiles = tt;
  }
}

/* ---------------- kernel 3: grouped gather-GEMM (R6 math, 3 blocks/CU) -----
   128x128 tile, BK=32, 4 waves (2M x 2N), per-wave 64x64 output.
   Triple-buffered LDS (48 KiB -> 3 blocks/CU, 12 waves/CU), depth-2
   prefetch, vmcnt(4), verified conflict-free swizzle, setprio, nt=bid&7
   XCD L2 pinning, dedup rep-write epilogue.                                */
__global__ __launch_bounds__(256, 3)
void k_gemm(const unsigned short* __restrict__ wsP,
            const unsigned short* __restrict__ wsW,
            const unsigned* __restrict__ tlist,
            const int* __restrict__ goff,
            const int* __restrict__ grows,
            const unsigned* __restrict__ table,
            const int* __restrict__ ntiles,
            float* __restrict__ out) {
  const int bid = blockIdx.x;
  const int mt = bid >> 3;
  const int nt = bid & 7;            /* nt == XCD: W slice stays in one L2 */
  if (mt >= *ntiles) return;

  const unsigned te = table[mt];
  const int l    = te & 15;
  const int row0 = (int)(te >> 4);
  const int toff = goff[l];
  const int rows = grows[l];

  __shared__ __align__(16) unsigned short As[3][BM * BK];  /* 3 x 8 KiB */
  __shared__ __align__(16) unsigned short Bs[3][BN * BK];  /* 3 x 8 KiB */

  const int tid  = threadIdx.x;
  const int lane = tid & 63;
  const int w    = tid >> 6;      /* 0..3 */
  const int wm   = w >> 1;        /* 0..1 : 64-row half */
  const int wn   = w & 1;         /* 0..1 : 64-col half */

  /* ---- staging source pointers (inverse-swizzled 16B slot on SOURCE) ----
     rows are 64 B; g(row) = (row>>1)&3 verified conflict-free in R6 */
  const int srow = tid >> 2;                       /* 0..63 */
  const int sx4  = ((tid & 3) ^ ((srow >> 1) & 3)) * 16;
  const char* aptr0;                               /* row  srow      */
  const char* aptr1;                               /* row  64+srow   */
  {
    long re[2];
#pragma unroll
    for (int r = 0; r < 2; ++r) {
      int rg = row0 + r * 64 + srow;
      if (rg < rows) {
        unsigned e = tlist[toff + (rg >> 3)];
        unsigned n = (e >> 12) & 0x3FF;
        int b = rg & 7;
        re[r] = (n >= N_) ? ZROW * (long)DIN
                          : ((long)(b * N_ + (int)n)) * DIN;
      } else re[r] = ZROW * (long)DIN;
    }
    aptr0 = (const char*)(wsP + re[0]) + sx4;
    aptr1 = (const char*)(wsP + re[1]) + sx4;
  }
  const char* bptr0 = (const char*)(wsW + ((long)l * DOUT + nt * BN + srow) * DIN) + sx4;
  const char* bptr1 = (const char*)(wsW + ((long)l * DOUT + nt * BN + 64 + srow) * DIN) + sx4;

/* stage one K-tile: A 128x32 (2 rounds) + B 128x32 (2 rounds), 4 loads/thr.
   LDS dest linear: wave-uniform base + lane*16 (HW). */
#define STG(t_, sb) do { \
  gload_lds16(aptr0 + (t_) * 64, (char*)As[sb] + w * 1024); \
  gload_lds16(aptr1 + (t_) * 64, (char*)As[sb] + 4096 + w * 1024); \
  gload_lds16(bptr0 + (t_) * 64, (char*)Bs[sb] + w * 1024); \
  gload_lds16(bptr1 + (t_) * 64, (char*)Bs[sb] + 4096 + w * 1024); } while (0)

  /* ---- fragment read offsets (same XOR on read side; R6-verified) ---- */
  const int arow = wm * 64 + (lane & 15);          /* LDS row of af[0] */
  const int brow = wn * 64 + (lane & 15);
  const int axr  = ((lane >> 4) ^ (((lane & 15) >> 1) & 3)) * 16;

  f32x4 acc[4][4];
#pragma unroll
  for (int m = 0; m < 4; ++m)
#pragma unroll
    for (int n = 0; n < 4; ++n)
      acc[m][n] = (f32x4){0.f, 0.f, 0.f, 0.f};

  short8 af[4], bf[4];

#define PHASE(t_, bb, sb) do { \
  const int t2_ = (t_) + 2; \
  if (t2_ < NKT) STG(t2_, sb); \
  _Pragma("unroll") for (int m_ = 0; m_ < 4; ++m_) \
    af[m_] = *(const short8*)((const char*)As[bb] + (arow + m_ * 16) * 64 + axr); \
  _Pragma("unroll") for (int n_ = 0; n_ < 4; ++n_) \
    bf[n_] = *(const short8*)((const char*)Bs[bb] + (brow + n_ * 16) * 64 + axr); \
  bar(); \
  asm volatile("s_waitcnt lgkmcnt(0)" ::: "memory"); \
  __builtin_amdgcn_s_setprio(1); \
  _Pragma("unroll") for (int n_ = 0; n_ < 4; ++n_) \
    _Pragma("unroll") for (int m_ = 0; m_ < 4; ++m_) \
      acc[m_][n_] = __builtin_amdgcn_mfma_f32_16x16x32_bf16(af[m_], bf[n_], acc[m_][n_], 0, 0, 0); \
  __builtin_amdgcn_s_setprio(0); \
  if (t2_ < NKT) asm volatile("s_waitcnt vmcnt(4)" ::: "memory"); \
  else           asm volatile("s_waitcnt vmcnt(0)" ::: "memory"); \
  bar(); \
} while (0)

  /* ---- prologue: tiles 0,1 -> bufs 0,1; tile0 complete before phase 0 ---- */
  STG(0, 0);
  STG(1, 1);
  asm volatile("s_waitcnt vmcnt(4)" ::: "memory");
  bar();

  for (int j = 0; j < 11; ++j) {
    const int t0 = 3 * j;
    if (t0     < NKT) PHASE(t0,     0, 2);
    if (t0 + 1 < NKT) PHASE(t0 + 1, 1, 0);
    if (t0 + 2 < NKT) PHASE(t0 + 2, 2, 1);
  }

  /* ---- epilogue: C/D layout col=lane&15, row=(lane>>4)*4+j; rep-write ---- */
#pragma unroll
  for (int m = 0; m < 4; ++m) {
#pragma unroll
    for (int jj = 0; jj < 4; ++jj) {
      int rt = wm * 64 + m * 16 + (lane >> 4) * 4 + jj;
      int rg = row0 + rt;
      if (rg >= rows) continue;
      unsigned e = tlist[toff + (rg >> 3)];
      int b = rg & 7;
      int t0 = (int)(e & 0xFFFu);
      int rep = (int)(e >> 22);
      float* orow = out + ((long)b * T_ + t0) * DOUT + nt * BN + wn * 64 + (lane & 15);
      for (int r = 0; r < rep; ++r) {
#pragma unroll
        for (int n = 0; n < 4; ++n)
          orow[n * 16] = acc[m][n][jj];
        orow += DOUT;
      }
    }
  }
#undef STG
#undef PHASE
}

/* ---------------- launch ---------------- */
extern "C" void kernel_launch(void* const* d_in, const int* in_sizes, int n_in,
                              void* d_out, int out_size, void* d_ws, size_t ws_size,
                              hipStream_t stream) {
  const float* pooled = (const float*)d_in[0];
  const float* W      = (const float*)d_in[1];
  const int*   pidx   = (const int*)d_in[2];
  float* out = (float*)d_out;

  char* ws = (char*)d_ws;
  unsigned short* wsP = (unsigned short*)(ws);
  unsigned short* wsW = (unsigned short*)(ws + WS_W_OFF);
  int* meta  = (int*)(ws + WS_META_OFF);
  unsigned* tlist = (unsigned*)meta;
  int* goff  = meta + 8 * T_;
  int* grows = meta + 8 * T_ + 16;
  unsigned* table = (unsigned*)(meta + 8 * T_ + 32);
  int* ntiles = meta + 8 * T_ + 32 + MT_MAX;

  k_prep<<<1, 512, 0, stream>>>(pidx, tlist, goff, grows, table, ntiles);
  k_convert<<<2048, 256, 0, stream>>>(pooled, W, wsP, wsW);
  k_gemm<<<MT_MAX * NB, 256, 0, stream>>>(wsP, wsW, tlist, goff, grows, table,
                                          ntiles, out);
}